// Round 12
// baseline (1824.314 us; speedup 1.0000x reference)
//
#include <hip/hip_runtime.h>
#include <hip/hip_fp16.h>
#include <math.h>

#define B_ 16
#define N_ 128
#define D_ 256
#define E_ 1024
#define GD4 1024      // 4*D
#define SENT 0xFFC0DEADu

typedef _Float16 h2 __attribute__((ext_vector_type(2)));
typedef _Float16 f16x8 __attribute__((ext_vector_type(8)));
typedef float f32x4 __attribute__((ext_vector_type(4)));

__device__ __forceinline__ float dot2w(unsigned w, h2 hv, float acc) {
#if __has_builtin(__builtin_amdgcn_fdot2)
  return __builtin_amdgcn_fdot2(__builtin_bit_cast(h2, w), hv, acc, false);
#else
  union { unsigned u; _Float16 e[2]; } c; c.u = w;
  return acc + (float)c.e[0]*(float)hv.x + (float)c.e[1]*(float)hv.y;
#endif
}
__device__ __forceinline__ float dot2h(h2 a, h2 b, float acc) {
#if __has_builtin(__builtin_amdgcn_fdot2)
  return __builtin_amdgcn_fdot2(a, b, acc, false);
#else
  return acc + (float)a.x*(float)b.x + (float)a.y*(float)b.y;
#endif
}

// ---------------------------------------------------------------------------
// fp32 tiled GEMM (NT) — kept for m2 (N=7).
// ---------------------------------------------------------------------------
template<bool BIAS, bool RELU>
__global__ __launch_bounds__(256) void gemm_k(const float* __restrict__ X,
    const float* __restrict__ W, const float* __restrict__ bias,
    float* __restrict__ C, int M, int N, int K)
{
  __shared__ float Xs[32][68];
  __shared__ float Ws[32][68];
  const int tid = threadIdx.x;
  const int m0 = blockIdx.x * 64, n0 = blockIdx.y * 64;
  const int tm = tid >> 4, tn = tid & 15;
  float acc[4][4] = {};
  for (int k0 = 0; k0 < K; k0 += 32) {
    for (int e = tid; e < 2048; e += 256) {
      int mm = e >> 5, kk = e & 31;
      Xs[kk][mm] = X[(m0+mm)*K + k0+kk];
    }
    for (int e = tid; e < 2048; e += 256) {
      int nn = e >> 5, kk = e & 31;
      Ws[kk][nn] = (n0+nn < N) ? W[(n0+nn)*K + k0+kk] : 0.f;
    }
    __syncthreads();
    for (int kk = 0; kk < 32; kk++) {
      float4 a = *(const float4*)&Xs[kk][tm*4];
      float4 b = *(const float4*)&Ws[kk][tn*4];
      acc[0][0] += a.x*b.x; acc[0][1] += a.x*b.y; acc[0][2] += a.x*b.z; acc[0][3] += a.x*b.w;
      acc[1][0] += a.y*b.x; acc[1][1] += a.y*b.y; acc[1][2] += a.y*b.z; acc[1][3] += a.y*b.w;
      acc[2][0] += a.z*b.x; acc[2][1] += a.z*b.y; acc[2][2] += a.z*b.z; acc[2][3] += a.z*b.w;
      acc[3][0] += a.w*b.x; acc[3][1] += a.w*b.y; acc[3][2] += a.w*b.z; acc[3][3] += a.w*b.w;
    }
    __syncthreads();
  }
  for (int i2 = 0; i2 < 4; i2++) {
    int row = m0 + tm*4 + i2;
    for (int j2 = 0; j2 < 4; j2++) {
      int col = n0 + tn*4 + j2;
      if (col < N) {
        float v = acc[i2][j2];
        if (BIAS) v += bias[col];
        if (RELU) v = fmaxf(v, 0.f);
        C[row*N + col] = v;
      }
    }
  }
}

// ---------------------------------------------------------------------------
// MFMA fp16 GEMM core helpers (64x64 tile, 4 waves of 2x2 16x16 sub-tiles).
// C/D: row=(l>>4)*4+j, col=l&15  [verified mapping]
// ---------------------------------------------------------------------------
__device__ __forceinline__ void mf_stage(const float* __restrict__ src,
    int ldsrc, _Float16 (*dst)[264], int tid)
{
  for (int e = tid; e < 8192; e += 256) {
    int row = e >> 7, cp = e & 127;
    float2 v = *(const float2*)&src[(size_t)row*ldsrc + 2*cp];
    h2 t; t.x = (_Float16)v.x; t.y = (_Float16)v.y;
    *(h2*)&dst[row][2*cp] = t;
  }
}

__device__ __forceinline__ void mf_compute(_Float16 (*Xh)[264],
    _Float16 (*Wh)[264], f32x4 acc[2][2], int l, int wr, int wc)
{
  #pragma unroll
  for (int kc = 0; kc < 256; kc += 32) {
    f16x8 a0 = *(const f16x8*)&Xh[wr*32 +      (l & 15)][kc + (l >> 4)*8];
    f16x8 a1 = *(const f16x8*)&Xh[wr*32 + 16 + (l & 15)][kc + (l >> 4)*8];
    f16x8 b0 = *(const f16x8*)&Wh[wc*32 +      (l & 15)][kc + (l >> 4)*8];
    f16x8 b1 = *(const f16x8*)&Wh[wc*32 + 16 + (l & 15)][kc + (l >> 4)*8];
    acc[0][0] = __builtin_amdgcn_mfma_f32_16x16x32_f16(a0, b0, acc[0][0], 0, 0, 0);
    acc[0][1] = __builtin_amdgcn_mfma_f32_16x16x32_f16(a0, b1, acc[0][1], 0, 0, 0);
    acc[1][0] = __builtin_amdgcn_mfma_f32_16x16x32_f16(a1, b0, acc[1][0], 0, 0, 0);
    acc[1][1] = __builtin_amdgcn_mfma_f32_16x16x32_f16(a1, b1, acc[1][1], 0, 0, 0);
  }
}

// Generic NT MFMA GEMM: C = [relu](X @ W^T + b). M,N mult of 64, K mult of 256.
template<bool BIAS, bool RELU>
__global__ __launch_bounds__(256) void mfgemm_k(const float* __restrict__ X,
    const float* __restrict__ W, const float* __restrict__ bias,
    float* __restrict__ C, int M, int N, int K)
{
  __shared__ _Float16 Xh[64][264];
  __shared__ _Float16 Wh[64][264];
  const int tid = threadIdx.x;
  const int m0 = blockIdx.x * 64, n0 = blockIdx.y * 64;
  const int l = tid & 63, w = tid >> 6;
  const int wr = w >> 1, wc = w & 1;
  f32x4 acc[2][2];
  #pragma unroll
  for (int rt = 0; rt < 2; ++rt)
    #pragma unroll
    for (int ct = 0; ct < 2; ++ct) acc[rt][ct] = 0.f;
  for (int k0 = 0; k0 < K; k0 += 256) {
    mf_stage(X + (size_t)m0*K + k0, K, Xh, tid);
    mf_stage(W + (size_t)n0*K + k0, K, Wh, tid);
    __syncthreads();
    mf_compute(Xh, Wh, acc, l, wr, wc);
    __syncthreads();
  }
  #pragma unroll
  for (int rt = 0; rt < 2; ++rt)
    #pragma unroll
    for (int ct = 0; ct < 2; ++ct)
      #pragma unroll
      for (int j = 0; j < 4; ++j) {
        int row = m0 + wr*32 + rt*16 + (l >> 4)*4 + j;
        int col = n0 + wc*32 + ct*16 + (l & 15);
        float v = acc[rt][ct][j];
        if (BIAS) v += bias[col];
        if (RELU) v = fmaxf(v, 0.f);
        C[(size_t)row*N + col] = v;
      }
}

// Fused per-layer prologue via MFMA (bias_sum folded in): GQC | GQP | VMAT.
__global__ __launch_bounds__(256) void prologue_mf_k(const float* __restrict__ X,
    const float* __restrict__ Wc, const float* __restrict__ Wp,
    const float* __restrict__ Am, const float* __restrict__ bci,
    const float* __restrict__ bch, const float* __restrict__ bpi,
    const float* __restrict__ bph, float* __restrict__ GQC,
    float* __restrict__ GQP, float* __restrict__ VM)
{
  __shared__ _Float16 Xh[64][264];
  __shared__ _Float16 Wh[64][264];
  const int tid = threadIdx.x;
  const int m0 = blockIdx.x * 64;
  const int nt = blockIdx.y;
  const float* W; const float* b0; const float* b1; float* C; int n0; int NC;
  if (nt < 16)      { W = Wc; b0 = bci; b1 = bch;  C = GQC; n0 = nt*64;      NC = 1024; }
  else if (nt < 32) { W = Wp; b0 = bpi; b1 = bph;  C = GQP; n0 = (nt-16)*64; NC = 1024; }
  else              { W = Am; b0 = nullptr; b1 = nullptr; C = VM; n0 = (nt-32)*64; NC = 256; }
  const int l = tid & 63, w = tid >> 6;
  const int wr = w >> 1, wc = w & 1;
  f32x4 acc[2][2];
  #pragma unroll
  for (int rt = 0; rt < 2; ++rt)
    #pragma unroll
    for (int ct = 0; ct < 2; ++ct) acc[rt][ct] = 0.f;
  mf_stage(X + (size_t)m0*256, 256, Xh, tid);
  mf_stage(W + (size_t)n0*256, 256, Wh, tid);
  __syncthreads();
  mf_compute(Xh, Wh, acc, l, wr, wc);
  __syncthreads();
  #pragma unroll
  for (int rt = 0; rt < 2; ++rt)
    #pragma unroll
    for (int ct = 0; ct < 2; ++ct)
      #pragma unroll
      for (int j = 0; j < 4; ++j) {
        int row = m0 + wr*32 + rt*16 + (l >> 4)*4 + j;
        int col = n0 + wc*32 + ct*16 + (l & 15);
        float v = acc[rt][ct][j];
        if (b0) v += b0[col] + b1[col];
        C[(size_t)row*NC + col] = v;
      }
}

// m0 fused with concat via MFMA. K=1792 in 7 chunks of 256.
__global__ __launch_bounds__(256) void m0fused_mf_k(const float* __restrict__ H0,
    const float* __restrict__ H1, const float* __restrict__ H2,
    const float* __restrict__ feat, const float* __restrict__ W,
    const float* __restrict__ bias, float* __restrict__ C)
{
  __shared__ _Float16 Xh[64][264];
  __shared__ _Float16 Wh[64][264];
  const int tid = threadIdx.x;
  const int m0 = blockIdx.x * 64, n0 = blockIdx.y * 64;
  const int l = tid & 63, w = tid >> 6;
  const int wr = w >> 1, wc = w & 1;
  f32x4 acc[2][2];
  #pragma unroll
  for (int rt = 0; rt < 2; ++rt)
    #pragma unroll
    for (int ct = 0; ct < 2; ++ct) acc[rt][ct] = 0.f;
  for (int k0 = 0; k0 < 1792; k0 += 256) {
    const float* src; int lds_; int coff;
    if (k0 == 0)        { src = H0;   lds_ = 256;  coff = 0; }
    else if (k0 == 256) { src = H1;   lds_ = 256;  coff = 0; }
    else if (k0 == 512) { src = H2;   lds_ = 256;  coff = 0; }
    else                { src = feat; lds_ = 1024; coff = k0 - 768; }
    mf_stage(src + (size_t)m0*lds_ + coff, lds_, Xh, tid);
    mf_stage(W + (size_t)n0*1792 + k0, 1792, Wh, tid);
    __syncthreads();
    mf_compute(Xh, Wh, acc, l, wr, wc);
    __syncthreads();
  }
  #pragma unroll
  for (int rt = 0; rt < 2; ++rt)
    #pragma unroll
    for (int ct = 0; ct < 2; ++ct)
      #pragma unroll
      for (int j = 0; j < 4; ++j) {
        int row = m0 + wr*32 + rt*16 + (l >> 4)*4 + j;
        int col = n0 + wc*32 + ct*16 + (l & 15);
        C[(size_t)row*256 + col] = fmaxf(acc[rt][ct][j] + bias[col], 0.f);
      }
}

// AMAT_l = W2_l^T @ W1_l, both layers.
__global__ __launch_bounds__(256) void prepamat_k(const float* __restrict__ W2,
    const float* __restrict__ W1, float* __restrict__ AM)
{
  __shared__ float Xs[32][68];
  __shared__ float Ws[32][68];
  const int tid = threadIdx.x;
  const int m0 = blockIdx.x * 64, n0 = blockIdx.y * 64;
  const float* X = W2 + blockIdx.z * 65536;
  const float* W = W1 + blockIdx.z * 65536;
  float* C = AM + blockIdx.z * 65536;
  const int tm = tid >> 4, tn = tid & 15;
  float acc[4][4] = {};
  for (int k0 = 0; k0 < 256; k0 += 32) {
    for (int e = tid; e < 2048; e += 256) {
      int kk = e >> 6, mm = e & 63;
      Xs[kk][mm] = X[(k0+kk)*256 + m0+mm];
    }
    for (int e = tid; e < 2048; e += 256) {
      int kk = e >> 6, nn = e & 63;
      Ws[kk][nn] = W[(k0+kk)*256 + n0+nn];
    }
    __syncthreads();
    for (int kk = 0; kk < 32; kk++) {
      float4 a = *(const float4*)&Xs[kk][tm*4];
      float4 b = *(const float4*)&Ws[kk][tn*4];
      acc[0][0] += a.x*b.x; acc[0][1] += a.x*b.y; acc[0][2] += a.x*b.z; acc[0][3] += a.x*b.w;
      acc[1][0] += a.y*b.x; acc[1][1] += a.y*b.y; acc[1][2] += a.y*b.z; acc[1][3] += a.y*b.w;
      acc[2][0] += a.z*b.x; acc[2][1] += a.z*b.y; acc[2][2] += a.z*b.z; acc[2][3] += a.z*b.w;
      acc[3][0] += a.w*b.x; acc[3][1] += a.w*b.y; acc[3][2] += a.w*b.z; acc[3][3] += a.w*b.w;
    }
    __syncthreads();
  }
  for (int i2 = 0; i2 < 4; i2++)
    for (int j2 = 0; j2 < 4; j2++)
      C[(m0 + tm*4 + i2)*256 + n0 + tn*4 + j2] = acc[i2][j2];
}

// [Wc_hh_l; Wp_ih_l] @ Wr_l (NN), both layers — writes PACKED fp16 WTP
// directly (gate rows g<8): half-index = l*589824 + sl*36864 + cq*1152 + r*8 + e.
__global__ __launch_bounds__(256) void prepnn_k(const float* __restrict__ Wch,
    const float* __restrict__ Wpi, const float* __restrict__ Wr,
    _Float16* __restrict__ WTP)
{
  __shared__ float Xs[32][68];
  __shared__ float Ws[32][68];
  const int tid = threadIdx.x;
  const int m0 = blockIdx.x * 64, n0 = blockIdx.y * 64;
  const int l = blockIdx.z;
  const float* X = (m0 < 1024) ? (Wch + l*262144 + m0*256)
                               : (Wpi + l*262144 + (m0-1024)*256);
  const float* W = Wr + l*65536;
  const int tm = tid >> 4, tn = tid & 15;
  float acc[4][4] = {};
  for (int k0 = 0; k0 < 256; k0 += 32) {
    for (int e = tid; e < 2048; e += 256) {
      int mm = e >> 5, kk = e & 31;
      Xs[kk][mm] = X[mm*256 + k0+kk];
    }
    for (int e = tid; e < 2048; e += 256) {
      int kk = e >> 6, nn = e & 63;
      Ws[kk][nn] = W[(k0+kk)*256 + n0+nn];
    }
    __syncthreads();
    for (int kk = 0; kk < 32; kk++) {
      float4 a = *(const float4*)&Xs[kk][tm*4];
      float4 b = *(const float4*)&Ws[kk][tn*4];
      acc[0][0] += a.x*b.x; acc[0][1] += a.x*b.y; acc[0][2] += a.x*b.z; acc[0][3] += a.x*b.w;
      acc[1][0] += a.y*b.x; acc[1][1] += a.y*b.y; acc[1][2] += a.y*b.z; acc[1][3] += a.y*b.w;
      acc[2][0] += a.z*b.x; acc[2][1] += a.z*b.y; acc[2][2] += a.z*b.z; acc[2][3] += a.z*b.w;
      acc[3][0] += a.w*b.x; acc[3][1] += a.w*b.y; acc[3][2] += a.w*b.z; acc[3][3] += a.w*b.w;
    }
    __syncthreads();
  }
  for (int i2 = 0; i2 < 4; i2++) {
    int row = m0 + tm*4 + i2;
    int g = (row < 1024) ? (row >> 8) : (4 + ((row - 1024) >> 8));
    int d = row & 255;
    int slp = d >> 4, dl = d & 15, r = g*16 + dl;
    size_t base = (size_t)l*589824 + (size_t)slp*36864 + r*8;
    for (int j2 = 0; j2 < 4; j2++) {
      int c = n0 + tn*4 + j2;
      WTP[base + (size_t)(c >> 3)*1152 + (c & 7)] = (_Float16)acc[i2][j2];
    }
  }
}

// Pack Wr rows (g=8) into WTP.
__global__ void wrpack_k(const float* __restrict__ wr, _Float16* __restrict__ WTP)
{
  int idx = blockIdx.x*256 + threadIdx.x;     // < 131072
  int l = idx >> 16; int rem = idx & 65535;
  int d = rem >> 8; int c = rem & 255;
  int slp = d >> 4, dl = d & 15;
  WTP[(size_t)l*589824 + (size_t)slp*36864 + (size_t)(c >> 3)*1152
      + (128 + dl)*8 + (c & 7)] = (_Float16)wr[l*65536 + d*256 + c];
}

// Sentinel-fill ONLY the polled word (word 15 of each 64B line) of H1/H2.
__global__ void fill_k(unsigned* __restrict__ a, unsigned* __restrict__ b)
{
  int i = blockIdx.x*256 + threadIdx.x;       // < 32768 lines per buffer
  if (i < 32768) {
    __hip_atomic_store(a + i*16 + 15, SENT, __ATOMIC_RELAXED, __HIP_MEMORY_SCOPE_AGENT);
    __hip_atomic_store(b + i*16 + 15, SENT, __ATOMIC_RELAXED, __HIP_MEMORY_SCOPE_AGENT);
  }
}

// ---------------------------------------------------------------------------
// Persistent scan (R9 structure, lean poll): G-decomposition, 3 barriers/step,
// wave-7 poll = 16 loads/iter (one lane per line, ballot-shared), NO s_sleep.
// ---------------------------------------------------------------------------
__device__ __forceinline__ float sigf(float x) { return 1.f / (1.f + __expf(-x)); }
__device__ __forceinline__ float tanhfast(float x) {
  float xc = fminf(fmaxf(x, -15.f), 15.f);
  float e = __expf(-2.f * xc);
  return (1.f - e) / (1.f + e);
}

__global__ __launch_bounds__(512, 2) void scan_k(
    const float* __restrict__ Hl,    // (B,N,D) layer input (Q source)
    const float* __restrict__ Vm,    // (B,N,D) Vmat
    const float* __restrict__ gqC,   // (B,N,4D)
    const float* __restrict__ gqP,   // (B,N,4D)
    const _Float16* __restrict__ WTp,// packed fp16 per-slice weights
    const int*   __restrict__ adj,   // (B,N,N)
    float* __restrict__ Hout)        // (B,N,D), word15s pre-filled with SENT
{
  __shared__ uint4 wl4[4608];              // 72KB fp16 weights [cq*144+r]
  __shared__ float G[128*144];             // 72KB G history [k*144+r]
  __shared__ __align__(8) _Float16 h2s[256];
  __shared__ float v_s[256];
  __shared__ __align__(8) _Float16 v2s[256];
  __shared__ float psum[128];
  __shared__ float aw[128];
  __shared__ int   adj_s[2][128];
  __shared__ float gqc_l[2][64], gqp_l[2][64];
  __shared__ float ql[2][16];
  __shared__ float Gg[144];
  __shared__ float red[2];
  __shared__ float sinv;

  const int tid = threadIdx.x;
  const int b   = blockIdx.x >> 4;
  const int sl  = blockIdx.x & 15;

  { const uint4* src = (const uint4*)WTp + (size_t)sl*4608;
    for (int e = tid; e < 4608; e += 512) wl4[e] = src[e]; }

  const int rr_ = tid >> 2;          // logit row 0..127
  const int rj  = tid & 3;           // quarter within row

#define PREF(ip_, bf_) do {                                                    \
    int ip = (ip_); int bf = (bf_);                                            \
    for (int u = tid - 288; u < 528; u += 224) {                               \
      if (u < 256) { float v = Vm[(b*N_ + ip)*D_ + u]; v_s[u] = v;             \
                     v2s[u] = (_Float16)v; }                                   \
      else if (u < 384) adj_s[bf][u-256] = adj[(b*N_ + ip)*N_ + (u-256)];      \
      else if (u < 448) gqc_l[bf][u-384] = gqC[(b*N_+ip)*GD4 + ((u-384)>>4)*D_ + sl*16 + ((u-384)&15)]; \
      else if (u < 512) gqp_l[bf][u-448] = gqP[(b*N_+ip)*GD4 + ((u-448)>>4)*D_ + sl*16 + ((u-448)&15)]; \
      else ql[bf][u-512] = Hl[(b*N_+ip)*D_ + sl*16 + (u-512)];                 \
    }                                                                          \
  } while (0)

  if (tid >= 288) PREF(0, 0);
  __syncthreads();

  for (int i = 0; i < N_; ++i) {
    const int cur = i & 1;
    if (i > 0) {
      // ---- pre-B1: proven-row logits (rows <= i-2); wave 7 polls+fetches --
      if (rr_ + 1 < i) {
        const float4* hp = (const float4*)(Hout + ((size_t)(b*N_ + rr_))*D_) + rj;
        const float4* vv = (const float4*)v_s + rj;
        float4 areg[16];
        #pragma unroll
        for (int c4 = 0; c4 < 16; ++c4) areg[c4] = hp[c4*4];
        float acc = 0.f;
        #pragma unroll
        for (int c4 = 0; c4 < 16; ++c4) {
          float4 a = areg[c4], w = vv[c4*4];
          acc += a.x*w.x + a.y*w.y + a.z*w.z + a.w*w.w;
        }
        acc += __shfl_xor(acc, 1, 64);
        acc += __shfl_xor(acc, 2, 64);
        if (rj == 0) psum[rr_] = acc;
      }
      if (tid >= 448) {                // wave 7: lean poll (16 loads/iter)
        int L = tid - 448;
        const unsigned* wp = (const unsigned*)Hout
                           + ((size_t)(b*N_ + (i-1)))*D_ + (L & 15)*16 + 15;
        unsigned v;
        do {
          v = (L < 16) ? __hip_atomic_load(wp, __ATOMIC_RELAXED, __HIP_MEMORY_SCOPE_AGENT)
                       : 0u;
        } while (__ballot((L < 16) && (v == SENT)));
        float4 hv = *((const float4*)(Hout + ((size_t)(b*N_ + (i-1)))*D_) + L);
        h2* hd = (h2*)h2s + L*2;
        h2 t0; t0.x = (_Float16)hv.x; t0.y = (_Float16)hv.y;
        h2 t1; t1.x = (_Float16)hv.z; t1.y = (_Float16)hv.w;
        hd[0] = t0; hd[1] = t1;
      }
      __syncthreads();                                       // B1
      asm volatile("" ::: "memory");

      // ---- post-B1: G[i-1] matvec | psum[i-1] | exp+Z ---------------------
      if (tid < 288) {
        int r = tid >> 1, hf = tid & 1;
        float acc2 = 0.f;
        #pragma unroll 4
        for (int it = 0; it < 16; ++it) {
          int cq = hf*16 + it;
          uint4 w4 = wl4[cq*144 + r];
          const h2* hh = (const h2*)h2s + cq*4;
          acc2 = dot2w(w4.x, hh[0], acc2);
          acc2 = dot2w(w4.y, hh[1], acc2);
          acc2 = dot2w(w4.z, hh[2], acc2);
          acc2 = dot2w(w4.w, hh[3], acc2);
        }
        acc2 += __shfl_xor(acc2, 1, 64);
        if (!hf) G[(i-1)*144 + r] = acc2;
      }
      if (rr_ == i-1) {                // 4 threads: logit for row i-1
        const h2* hh = (const h2*)h2s + rj*32;
        const h2* vv = (const h2*)v2s + rj*32;
        float acc = 0.f;
        #pragma unroll 8
        for (int q = 0; q < 32; ++q) acc = dot2h(hh[q], vv[q], acc);
        acc += __shfl_xor(acc, 1, 64);
        acc += __shfl_xor(acc, 2, 64);
        if (rj == 0) psum[i-1] = acc;
      }
      if (tid >= 320 && tid < 448) {   // exp + Z over k <= i-2
        int k = tid - 320;
        float e = (k + 1 < i && adj_s[cur][k] != 0) ? __expf(psum[k]) : 0.f;
        aw[k] = e;
        float sv = e;
        #pragma unroll
        for (int off = 32; off >= 1; off >>= 1) sv += __shfl_xor(sv, off, 64);
        if ((k & 63) == 0) red[k >> 6] = sv;
      }
      __syncthreads();                                       // B2

      // ---- post-B2: Gsum + sinv (tid<288) | prefetch i+1 (tid>=288) -------
      if (tid < 288) {
        int r = tid >> 1, kh = tid & 1;
        float e1 = (adj_s[cur][i-1] != 0) ? __expf(psum[i-1]) : 0.f;
        float g = kh ? e1 * G[(i-1)*144 + r] : 0.f;
        int m = i - 1;
        int k0 = kh ? (m >> 1) : 0, k1 = kh ? m : (m >> 1);
        for (int k = k0; k < k1; ++k) g += aw[k] * G[k*144 + r];
        g += __shfl_xor(g, 1, 64);
        if (!kh) Gg[r] = g;
        if (tid == 0) sinv = 1.f / (red[0] + red[1] + e1);
      } else {
        PREF((i < 127) ? i+1 : 127, (i+1) & 1);
      }
      __syncthreads();                                       // B3
    } else {
      if (tid >= 288) PREF(1, 1);
      __syncthreads();
    }

    // ---- gates: 32 lanes, 2 per d (cell 0 = C, cell 1 = P) ----------------
    if (tid < 32) {
      int dl = tid >> 1, cell = tid & 1;
      float inv = (i > 0) ? sinv : 0.f;
      float r0 = 0.f, r1 = 0.f, r2 = 0.f, r3 = 0.f, Mv = 0.f;
      if (i > 0) {
        r0 = Gg[(cell*4+0)*16 + dl] * inv;
        r1 = Gg[(cell*4+1)*16 + dl] * inv;
        r2 = Gg[(cell*4+2)*16 + dl] * inv;
        r3 = Gg[(cell*4+3)*16 + dl] * inv;
        Mv = Gg[128 + dl] * inv;
      }
      float Qv = ql[cur][dl];
      const float* gq = cell ? &gqp_l[cur][0] : &gqc_l[cur][0];
      float xi = cell ? Qv : Mv;
      float gi_ = r0 + gq[ 0 + dl];
      float gf_ = r1 + gq[16 + dl];
      float gg_ = r2 + gq[32 + dl];
      float go_ = r3 + gq[48 + dl];
      float c2  = sigf(gf_)*xi + sigf(gi_)*tanhfast(gg_);
      float ov  = sigf(go_)*tanhfast(c2);
      float htv = ov + __shfl_xor(ov, 1, 64);
      if (!cell) {                     // 16 lanes -> one 64B line store
        __hip_atomic_store(&Hout[((size_t)(b*N_ + i))*D_ + sl*16 + dl], htv,
                           __ATOMIC_RELAXED, __HIP_MEMORY_SCOPE_AGENT);
      }
    }
    // no trailing barrier: wave 0 reaches next B1 only after gates complete;
    // the line store IS the publish signal (consumers poll it directly).
  }
#undef PREF
}

// ---------------------------------------------------------------------------
// Host launch
// ---------------------------------------------------------------------------
extern "C" void kernel_launch(void* const* d_in, const int* in_sizes, int n_in,
                              void* d_out, int out_size, void* d_ws, size_t ws_size,
                              hipStream_t stream)
{
  const float* features = (const float*)d_in[0];
  const int*   adj      = (const int*)  d_in[1];
  const float* fc1_W    = (const float*)d_in[5];
  const float* fc1_b    = (const float*)d_in[6];
  const float* W1       = (const float*)d_in[7];
  const float* W2       = (const float*)d_in[8];
  const float* Wr       = (const float*)d_in[9];
  const float* Wc_ih    = (const float*)d_in[10];
  const float* Wc_hh    = (const float*)d_in[11];
  const float* bc_ih    = (const float*)d_in[12];
  const float* bc_hh    = (const float*)d_in[13];
  const float* Wp_ih    = (const float*)d_in[14];
  const float* Wp_hh    = (const float*)d_in[15];
  const float* bp_ih    = (const float*)d_in[16];
  const float* bp_hh    = (const float*)d_in[17];
  const float* m0_W     = (const float*)d_in[18];
  const float* m0_b     = (const float*)d_in[19];
  const float* m1_W     = (const float*)d_in[20];
  const float* m1_b     = (const float*)d_in[21];
  const float* m2_W     = (const float*)d_in[22];
  const float* m2_b     = (const float*)d_in[23];

  float* ws = (float*)d_ws;
  _Float16* WTP = (_Float16*)ws;     // 1179648 halfs = 589824 float slots
  float* AMAT   = ws + 589824;       // 2 x 65536
  float* H0     = ws + 720896;       // 524288
  float* H1     = ws + 1245184;      // 524288
  float* H2     = ws + 1769472;      // 524288
  float* VMAT   = ws + 2293760;      // 524288
  float* GQC    = ws + 2818048;      // 2097152
  float* GQP    = ws + 4915200;      // 2097152
  float* HB1    = ws + 7012352;      // 524288
  float* HB2    = ws + 7536640;      // 524288

  fill_k<<<128, 256, 0, stream>>>((unsigned*)H1, (unsigned*)H2);
  prepamat_k<<<dim3(4,4,2), 256, 0, stream>>>(W2, W1, AMAT);
  prepnn_k<<<dim3(32,4,2), 256, 0, stream>>>(Wc_hh, Wp_ih, Wr, WTP);
  wrpack_k<<<512, 256, 0, stream>>>(Wr, WTP);

  // H0 = relu(features @ fc1_W^T + b)  (MFMA fp16)
  mfgemm_k<true,true><<<dim3(32,4), 256, 0, stream>>>(features, fc1_W, fc1_b, H0, 2048, 256, 1024);

  // layer 0
  prologue_mf_k<<<dim3(32,36), 256, 0, stream>>>(H0, Wc_ih, Wp_hh, AMAT,
                                                 bc_ih, bc_hh, bp_ih, bp_hh,
                                                 GQC, GQP, VMAT);
  scan_k<<<256, 512, 0, stream>>>(H0, VMAT, GQC, GQP, WTP, adj, H1);

  // layer 1
  prologue_mf_k<<<dim3(32,36), 256, 0, stream>>>(H1, Wc_ih + 262144, Wp_hh + 262144,
                                                 AMAT + 65536,
                                                 bc_ih + 1024, bc_hh + 1024,
                                                 bp_ih + 1024, bp_hh + 1024,
                                                 GQC, GQP, VMAT);
  scan_k<<<256, 512, 0, stream>>>(H1, VMAT, GQC, GQP, WTP + 589824, adj, H2);

  // MLP head
  m0fused_mf_k<<<dim3(32,4), 256, 0, stream>>>(H0, H1, H2, features, m0_W, m0_b, HB1);
  mfgemm_k<true,true><<<dim3(32,4), 256, 0, stream>>>(HB1, m1_W, m1_b, HB2, 2048, 256, 256);
  gemm_k<true,false><<<dim3(32,1), 256, 0, stream>>>(HB2, m2_W, m2_b, (float*)d_out, 2048, 7, 256);
}

// Round 14
// 1773.289 us; speedup vs baseline: 1.0288x; 1.0288x over previous
//
#include <hip/hip_runtime.h>
#include <hip/hip_fp16.h>
#include <math.h>

#define B_ 16
#define N_ 128
#define D_ 256
#define E_ 1024
#define GD4 1024      // 4*D
#define SENT 0xFFC0DEADu

typedef _Float16 h2 __attribute__((ext_vector_type(2)));
typedef _Float16 f16x8 __attribute__((ext_vector_type(8)));
typedef float f32x4 __attribute__((ext_vector_type(4)));

__device__ __forceinline__ float dot2w(unsigned w, h2 hv, float acc) {
#if __has_builtin(__builtin_amdgcn_fdot2)
  return __builtin_amdgcn_fdot2(__builtin_bit_cast(h2, w), hv, acc, false);
#else
  union { unsigned u; _Float16 e[2]; } c; c.u = w;
  return acc + (float)c.e[0]*(float)hv.x + (float)c.e[1]*(float)hv.y;
#endif
}
__device__ __forceinline__ float dot2h(h2 a, h2 b, float acc) {
#if __has_builtin(__builtin_amdgcn_fdot2)
  return __builtin_amdgcn_fdot2(a, b, acc, false);
#else
  return acc + (float)a.x*(float)b.x + (float)a.y*(float)b.y;
#endif
}

// ---------------------------------------------------------------------------
// fp32 tiled GEMM (NT) — kept for m2 (N=7).
// ---------------------------------------------------------------------------
template<bool BIAS, bool RELU>
__global__ __launch_bounds__(256) void gemm_k(const float* __restrict__ X,
    const float* __restrict__ W, const float* __restrict__ bias,
    float* __restrict__ C, int M, int N, int K)
{
  __shared__ float Xs[32][68];
  __shared__ float Ws[32][68];
  const int tid = threadIdx.x;
  const int m0 = blockIdx.x * 64, n0 = blockIdx.y * 64;
  const int tm = tid >> 4, tn = tid & 15;
  float acc[4][4] = {};
  for (int k0 = 0; k0 < K; k0 += 32) {
    for (int e = tid; e < 2048; e += 256) {
      int mm = e >> 5, kk = e & 31;
      Xs[kk][mm] = X[(m0+mm)*K + k0+kk];
    }
    for (int e = tid; e < 2048; e += 256) {
      int nn = e >> 5, kk = e & 31;
      Ws[kk][nn] = (n0+nn < N) ? W[(n0+nn)*K + k0+kk] : 0.f;
    }
    __syncthreads();
    for (int kk = 0; kk < 32; kk++) {
      float4 a = *(const float4*)&Xs[kk][tm*4];
      float4 b = *(const float4*)&Ws[kk][tn*4];
      acc[0][0] += a.x*b.x; acc[0][1] += a.x*b.y; acc[0][2] += a.x*b.z; acc[0][3] += a.x*b.w;
      acc[1][0] += a.y*b.x; acc[1][1] += a.y*b.y; acc[1][2] += a.y*b.z; acc[1][3] += a.y*b.w;
      acc[2][0] += a.z*b.x; acc[2][1] += a.z*b.y; acc[2][2] += a.z*b.z; acc[2][3] += a.z*b.w;
      acc[3][0] += a.w*b.x; acc[3][1] += a.w*b.y; acc[3][2] += a.w*b.z; acc[3][3] += a.w*b.w;
    }
    __syncthreads();
  }
  for (int i2 = 0; i2 < 4; i2++) {
    int row = m0 + tm*4 + i2;
    for (int j2 = 0; j2 < 4; j2++) {
      int col = n0 + tn*4 + j2;
      if (col < N) {
        float v = acc[i2][j2];
        if (BIAS) v += bias[col];
        if (RELU) v = fmaxf(v, 0.f);
        C[row*N + col] = v;
      }
    }
  }
}

// ---------------------------------------------------------------------------
// MFMA fp16 GEMM core helpers (64x64 tile, 4 waves of 2x2 16x16 sub-tiles).
// C/D: row=(l>>4)*4+j, col=l&15  [verified mapping]
// ---------------------------------------------------------------------------
__device__ __forceinline__ void mf_stage(const float* __restrict__ src,
    int ldsrc, _Float16 (*dst)[264], int tid)
{
  for (int e = tid; e < 8192; e += 256) {
    int row = e >> 7, cp = e & 127;
    float2 v = *(const float2*)&src[(size_t)row*ldsrc + 2*cp];
    h2 t; t.x = (_Float16)v.x; t.y = (_Float16)v.y;
    *(h2*)&dst[row][2*cp] = t;
  }
}

__device__ __forceinline__ void mf_compute(_Float16 (*Xh)[264],
    _Float16 (*Wh)[264], f32x4 acc[2][2], int l, int wr, int wc)
{
  #pragma unroll
  for (int kc = 0; kc < 256; kc += 32) {
    f16x8 a0 = *(const f16x8*)&Xh[wr*32 +      (l & 15)][kc + (l >> 4)*8];
    f16x8 a1 = *(const f16x8*)&Xh[wr*32 + 16 + (l & 15)][kc + (l >> 4)*8];
    f16x8 b0 = *(const f16x8*)&Wh[wc*32 +      (l & 15)][kc + (l >> 4)*8];
    f16x8 b1 = *(const f16x8*)&Wh[wc*32 + 16 + (l & 15)][kc + (l >> 4)*8];
    acc[0][0] = __builtin_amdgcn_mfma_f32_16x16x32_f16(a0, b0, acc[0][0], 0, 0, 0);
    acc[0][1] = __builtin_amdgcn_mfma_f32_16x16x32_f16(a0, b1, acc[0][1], 0, 0, 0);
    acc[1][0] = __builtin_amdgcn_mfma_f32_16x16x32_f16(a1, b0, acc[1][0], 0, 0, 0);
    acc[1][1] = __builtin_amdgcn_mfma_f32_16x16x32_f16(a1, b1, acc[1][1], 0, 0, 0);
  }
}

// Generic NT MFMA GEMM: C = [relu](X @ W^T + b). M,N mult of 64, K mult of 256.
template<bool BIAS, bool RELU>
__global__ __launch_bounds__(256) void mfgemm_k(const float* __restrict__ X,
    const float* __restrict__ W, const float* __restrict__ bias,
    float* __restrict__ C, int M, int N, int K)
{
  __shared__ _Float16 Xh[64][264];
  __shared__ _Float16 Wh[64][264];
  const int tid = threadIdx.x;
  const int m0 = blockIdx.x * 64, n0 = blockIdx.y * 64;
  const int l = tid & 63, w = tid >> 6;
  const int wr = w >> 1, wc = w & 1;
  f32x4 acc[2][2];
  #pragma unroll
  for (int rt = 0; rt < 2; ++rt)
    #pragma unroll
    for (int ct = 0; ct < 2; ++ct) acc[rt][ct] = 0.f;
  for (int k0 = 0; k0 < K; k0 += 256) {
    mf_stage(X + (size_t)m0*K + k0, K, Xh, tid);
    mf_stage(W + (size_t)n0*K + k0, K, Wh, tid);
    __syncthreads();
    mf_compute(Xh, Wh, acc, l, wr, wc);
    __syncthreads();
  }
  #pragma unroll
  for (int rt = 0; rt < 2; ++rt)
    #pragma unroll
    for (int ct = 0; ct < 2; ++ct)
      #pragma unroll
      for (int j = 0; j < 4; ++j) {
        int row = m0 + wr*32 + rt*16 + (l >> 4)*4 + j;
        int col = n0 + wc*32 + ct*16 + (l & 15);
        float v = acc[rt][ct][j];
        if (BIAS) v += bias[col];
        if (RELU) v = fmaxf(v, 0.f);
        C[(size_t)row*N + col] = v;
      }
}

// Fused per-layer prologue via MFMA (bias_sum folded in): GQC | GQP | VMAT.
__global__ __launch_bounds__(256) void prologue_mf_k(const float* __restrict__ X,
    const float* __restrict__ Wc, const float* __restrict__ Wp,
    const float* __restrict__ Am, const float* __restrict__ bci,
    const float* __restrict__ bch, const float* __restrict__ bpi,
    const float* __restrict__ bph, float* __restrict__ GQC,
    float* __restrict__ GQP, float* __restrict__ VM)
{
  __shared__ _Float16 Xh[64][264];
  __shared__ _Float16 Wh[64][264];
  const int tid = threadIdx.x;
  const int m0 = blockIdx.x * 64;
  const int nt = blockIdx.y;
  const float* W; const float* b0; const float* b1; float* C; int n0; int NC;
  if (nt < 16)      { W = Wc; b0 = bci; b1 = bch;  C = GQC; n0 = nt*64;      NC = 1024; }
  else if (nt < 32) { W = Wp; b0 = bpi; b1 = bph;  C = GQP; n0 = (nt-16)*64; NC = 1024; }
  else              { W = Am; b0 = nullptr; b1 = nullptr; C = VM; n0 = (nt-32)*64; NC = 256; }
  const int l = tid & 63, w = tid >> 6;
  const int wr = w >> 1, wc = w & 1;
  f32x4 acc[2][2];
  #pragma unroll
  for (int rt = 0; rt < 2; ++rt)
    #pragma unroll
    for (int ct = 0; ct < 2; ++ct) acc[rt][ct] = 0.f;
  mf_stage(X + (size_t)m0*256, 256, Xh, tid);
  mf_stage(W + (size_t)n0*256, 256, Wh, tid);
  __syncthreads();
  mf_compute(Xh, Wh, acc, l, wr, wc);
  __syncthreads();
  #pragma unroll
  for (int rt = 0; rt < 2; ++rt)
    #pragma unroll
    for (int ct = 0; ct < 2; ++ct)
      #pragma unroll
      for (int j = 0; j < 4; ++j) {
        int row = m0 + wr*32 + rt*16 + (l >> 4)*4 + j;
        int col = n0 + wc*32 + ct*16 + (l & 15);
        float v = acc[rt][ct][j];
        if (b0) v += b0[col] + b1[col];
        C[(size_t)row*NC + col] = v;
      }
}

// m0 fused with concat via MFMA. K=1792 in 7 chunks of 256.
__global__ __launch_bounds__(256) void m0fused_mf_k(const float* __restrict__ H0,
    const float* __restrict__ H1, const float* __restrict__ H2,
    const float* __restrict__ feat, const float* __restrict__ W,
    const float* __restrict__ bias, float* __restrict__ C)
{
  __shared__ _Float16 Xh[64][264];
  __shared__ _Float16 Wh[64][264];
  const int tid = threadIdx.x;
  const int m0 = blockIdx.x * 64, n0 = blockIdx.y * 64;
  const int l = tid & 63, w = tid >> 6;
  const int wr = w >> 1, wc = w & 1;
  f32x4 acc[2][2];
  #pragma unroll
  for (int rt = 0; rt < 2; ++rt)
    #pragma unroll
    for (int ct = 0; ct < 2; ++ct) acc[rt][ct] = 0.f;
  for (int k0 = 0; k0 < 1792; k0 += 256) {
    const float* src; int lds_; int coff;
    if (k0 == 0)        { src = H0;   lds_ = 256;  coff = 0; }
    else if (k0 == 256) { src = H1;   lds_ = 256;  coff = 0; }
    else if (k0 == 512) { src = H2;   lds_ = 256;  coff = 0; }
    else                { src = feat; lds_ = 1024; coff = k0 - 768; }
    mf_stage(src + (size_t)m0*lds_ + coff, lds_, Xh, tid);
    mf_stage(W + (size_t)n0*1792 + k0, 1792, Wh, tid);
    __syncthreads();
    mf_compute(Xh, Wh, acc, l, wr, wc);
    __syncthreads();
  }
  #pragma unroll
  for (int rt = 0; rt < 2; ++rt)
    #pragma unroll
    for (int ct = 0; ct < 2; ++ct)
      #pragma unroll
      for (int j = 0; j < 4; ++j) {
        int row = m0 + wr*32 + rt*16 + (l >> 4)*4 + j;
        int col = n0 + wc*32 + ct*16 + (l & 15);
        C[(size_t)row*256 + col] = fmaxf(acc[rt][ct][j] + bias[col], 0.f);
      }
}

// AMAT_l = W2_l^T @ W1_l, both layers.
__global__ __launch_bounds__(256) void prepamat_k(const float* __restrict__ W2,
    const float* __restrict__ W1, float* __restrict__ AM)
{
  __shared__ float Xs[32][68];
  __shared__ float Ws[32][68];
  const int tid = threadIdx.x;
  const int m0 = blockIdx.x * 64, n0 = blockIdx.y * 64;
  const float* X = W2 + blockIdx.z * 65536;
  const float* W = W1 + blockIdx.z * 65536;
  float* C = AM + blockIdx.z * 65536;
  const int tm = tid >> 4, tn = tid & 15;
  float acc[4][4] = {};
  for (int k0 = 0; k0 < 256; k0 += 32) {
    for (int e = tid; e < 2048; e += 256) {
      int kk = e >> 6, mm = e & 63;
      Xs[kk][mm] = X[(k0+kk)*256 + m0+mm];
    }
    for (int e = tid; e < 2048; e += 256) {
      int kk = e >> 6, nn = e & 63;
      Ws[kk][nn] = W[(k0+kk)*256 + n0+nn];
    }
    __syncthreads();
    for (int kk = 0; kk < 32; kk++) {
      float4 a = *(const float4*)&Xs[kk][tm*4];
      float4 b = *(const float4*)&Ws[kk][tn*4];
      acc[0][0] += a.x*b.x; acc[0][1] += a.x*b.y; acc[0][2] += a.x*b.z; acc[0][3] += a.x*b.w;
      acc[1][0] += a.y*b.x; acc[1][1] += a.y*b.y; acc[1][2] += a.y*b.z; acc[1][3] += a.y*b.w;
      acc[2][0] += a.z*b.x; acc[2][1] += a.z*b.y; acc[2][2] += a.z*b.z; acc[2][3] += a.z*b.w;
      acc[3][0] += a.w*b.x; acc[3][1] += a.w*b.y; acc[3][2] += a.w*b.z; acc[3][3] += a.w*b.w;
    }
    __syncthreads();
  }
  for (int i2 = 0; i2 < 4; i2++)
    for (int j2 = 0; j2 < 4; j2++)
      C[(m0 + tm*4 + i2)*256 + n0 + tn*4 + j2] = acc[i2][j2];
}

// [Wc_hh_l; Wp_ih_l] @ Wr_l (NN), both layers — writes PACKED fp16 WTP
// directly (gate rows g<8).
__global__ __launch_bounds__(256) void prepnn_k(const float* __restrict__ Wch,
    const float* __restrict__ Wpi, const float* __restrict__ Wr,
    _Float16* __restrict__ WTP)
{
  __shared__ float Xs[32][68];
  __shared__ float Ws[32][68];
  const int tid = threadIdx.x;
  const int m0 = blockIdx.x * 64, n0 = blockIdx.y * 64;
  const int l = blockIdx.z;
  const float* X = (m0 < 1024) ? (Wch + l*262144 + m0*256)
                               : (Wpi + l*262144 + (m0-1024)*256);
  const float* W = Wr + l*65536;
  const int tm = tid >> 4, tn = tid & 15;
  float acc[4][4] = {};
  for (int k0 = 0; k0 < 256; k0 += 32) {
    for (int e = tid; e < 2048; e += 256) {
      int mm = e >> 5, kk = e & 31;
      Xs[kk][mm] = X[mm*256 + k0+kk];
    }
    for (int e = tid; e < 2048; e += 256) {
      int kk = e >> 6, nn = e & 63;
      Ws[kk][nn] = W[(k0+kk)*256 + n0+nn];
    }
    __syncthreads();
    for (int kk = 0; kk < 32; kk++) {
      float4 a = *(const float4*)&Xs[kk][tm*4];
      float4 b = *(const float4*)&Ws[kk][tn*4];
      acc[0][0] += a.x*b.x; acc[0][1] += a.x*b.y; acc[0][2] += a.x*b.z; acc[0][3] += a.x*b.w;
      acc[1][0] += a.y*b.x; acc[1][1] += a.y*b.y; acc[1][2] += a.y*b.z; acc[1][3] += a.y*b.w;
      acc[2][0] += a.z*b.x; acc[2][1] += a.z*b.y; acc[2][2] += a.z*b.z; acc[2][3] += a.z*b.w;
      acc[3][0] += a.w*b.x; acc[3][1] += a.w*b.y; acc[3][2] += a.w*b.z; acc[3][3] += a.w*b.w;
    }
    __syncthreads();
  }
  for (int i2 = 0; i2 < 4; i2++) {
    int row = m0 + tm*4 + i2;
    int g = (row < 1024) ? (row >> 8) : (4 + ((row - 1024) >> 8));
    int d = row & 255;
    int slp = d >> 4, dl = d & 15, r = g*16 + dl;
    size_t base = (size_t)l*589824 + (size_t)slp*36864 + r*8;
    for (int j2 = 0; j2 < 4; j2++) {
      int c = n0 + tn*4 + j2;
      WTP[base + (size_t)(c >> 3)*1152 + (c & 7)] = (_Float16)acc[i2][j2];
    }
  }
}

// Pack Wr rows (g=8) into WTP.
__global__ void wrpack_k(const float* __restrict__ wr, _Float16* __restrict__ WTP)
{
  int idx = blockIdx.x*256 + threadIdx.x;     // < 131072
  int l = idx >> 16; int rem = idx & 65535;
  int d = rem >> 8; int c = rem & 255;
  int slp = d >> 4, dl = d & 15;
  WTP[(size_t)l*589824 + (size_t)slp*36864 + (size_t)(c >> 3)*1152
      + (128 + dl)*8 + (c & 7)] = (_Float16)wr[l*65536 + d*256 + c];
}

// Sentinel-fill ONLY the polled word (word 15 of each 64B line) of H1/H2.
__global__ void fill_k(unsigned* __restrict__ a, unsigned* __restrict__ b)
{
  int i = blockIdx.x*256 + threadIdx.x;       // < 32768 lines per buffer
  if (i < 32768) {
    __hip_atomic_store(a + i*16 + 15, SENT, __ATOMIC_RELAXED, __HIP_MEMORY_SCOPE_AGENT);
    __hip_atomic_store(b + i*16 + 15, SENT, __ATOMIC_RELAXED, __HIP_MEMORY_SCOPE_AGENT);
  }
}

// ---------------------------------------------------------------------------
// Persistent scan (R9 structure — best validated): G-decomposition,
// 3 barriers/step, wave-7 sentinel poll (bypass dword + s_sleep) then cached
// row re-fetch. Publish: 16-lane 64B line store (write-through, relaxed).
// ---------------------------------------------------------------------------
__device__ __forceinline__ float sigf(float x) { return 1.f / (1.f + __expf(-x)); }
__device__ __forceinline__ float tanhfast(float x) {
  float xc = fminf(fmaxf(x, -15.f), 15.f);
  float e = __expf(-2.f * xc);
  return (1.f - e) / (1.f + e);
}

__global__ __launch_bounds__(512, 2) void scan_k(
    const float* __restrict__ Hl,    // (B,N,D) layer input (Q source)
    const float* __restrict__ Vm,    // (B,N,D) Vmat
    const float* __restrict__ gqC,   // (B,N,4D)
    const float* __restrict__ gqP,   // (B,N,4D)
    const _Float16* __restrict__ WTp,// packed fp16 per-slice weights
    const int*   __restrict__ adj,   // (B,N,N)
    float* __restrict__ Hout)        // (B,N,D), word15s pre-filled with SENT
{
  __shared__ uint4 wl4[4608];              // 72KB fp16 weights [cq*144+r]
  __shared__ float G[128*144];             // 72KB G history [k*144+r]
  __shared__ __align__(8) _Float16 h2s[256];
  __shared__ float v_s[256];
  __shared__ __align__(8) _Float16 v2s[256];
  __shared__ float psum[128];
  __shared__ float aw[128];
  __shared__ int   adj_s[2][128];
  __shared__ float gqc_l[2][64], gqp_l[2][64];
  __shared__ float ql[2][16];
  __shared__ float Gg[144];
  __shared__ float red[2];
  __shared__ float sinv;

  const int tid = threadIdx.x;
  const int b   = blockIdx.x >> 4;
  const int sl  = blockIdx.x & 15;

  { const uint4* src = (const uint4*)WTp + (size_t)sl*4608;
    for (int e = tid; e < 4608; e += 512) wl4[e] = src[e]; }

  const int rr_ = tid >> 2;          // logit row 0..127
  const int rj  = tid & 3;           // quarter within row

#define PREF(ip_, bf_) do {                                                    \
    int ip = (ip_); int bf = (bf_);                                            \
    for (int u = tid - 288; u < 528; u += 224) {                               \
      if (u < 256) { float v = Vm[(b*N_ + ip)*D_ + u]; v_s[u] = v;             \
                     v2s[u] = (_Float16)v; }                                   \
      else if (u < 384) adj_s[bf][u-256] = adj[(b*N_ + ip)*N_ + (u-256)];      \
      else if (u < 448) gqc_l[bf][u-384] = gqC[(b*N_+ip)*GD4 + ((u-384)>>4)*D_ + sl*16 + ((u-384)&15)]; \
      else if (u < 512) gqp_l[bf][u-448] = gqP[(b*N_+ip)*GD4 + ((u-448)>>4)*D_ + sl*16 + ((u-448)&15)]; \
      else ql[bf][u-512] = Hl[(b*N_+ip)*D_ + sl*16 + (u-512)];                 \
    }                                                                          \
  } while (0)

  if (tid >= 288) PREF(0, 0);
  __syncthreads();

  for (int i = 0; i < N_; ++i) {
    const int cur = i & 1;
    if (i > 0) {
      // ---- pre-B1: proven-row logits (rows <= i-2); wave 7 polls+fetches --
      if (rr_ + 1 < i) {
        const float4* hp = (const float4*)(Hout + ((size_t)(b*N_ + rr_))*D_) + rj;
        const float4* vv = (const float4*)v_s + rj;
        float4 areg[16];
        #pragma unroll
        for (int c4 = 0; c4 < 16; ++c4) areg[c4] = hp[c4*4];
        float acc = 0.f;
        #pragma unroll
        for (int c4 = 0; c4 < 16; ++c4) {
          float4 a = areg[c4], w = vv[c4*4];
          acc += a.x*w.x + a.y*w.y + a.z*w.z + a.w*w.w;
        }
        acc += __shfl_xor(acc, 1, 64);
        acc += __shfl_xor(acc, 2, 64);
        if (rj == 0) psum[rr_] = acc;
      }
      if (tid >= 448) {                // wave 7: poll 16 lines (4 lanes/line)
        const unsigned* wp = (const unsigned*)Hout
                           + ((size_t)(b*N_ + (i-1)))*D_ + ((tid-448)&15)*16 + 15;
        while (__hip_atomic_load(wp, __ATOMIC_RELAXED, __HIP_MEMORY_SCOPE_AGENT) == SENT)
          __builtin_amdgcn_s_sleep(1);
        int lane = tid - 448;          // 64 lanes x float4 = row i-1
        float4 hv = *((const float4*)(Hout + ((size_t)(b*N_ + (i-1)))*D_) + lane);
        h2* hd = (h2*)h2s + lane*2;
        h2 t0; t0.x = (_Float16)hv.x; t0.y = (_Float16)hv.y;
        h2 t1; t1.x = (_Float16)hv.z; t1.y = (_Float16)hv.w;
        hd[0] = t0; hd[1] = t1;
      }
      __syncthreads();                                       // B1
      asm volatile("" ::: "memory");

      // ---- post-B1: G[i-1] matvec | psum[i-1] | exp+Z ---------------------
      if (tid < 288) {
        int r = tid >> 1, hf = tid & 1;
        float acc2 = 0.f;
        #pragma unroll 4
        for (int it = 0; it < 16; ++it) {
          int cq = hf*16 + it;
          uint4 w4 = wl4[cq*144 + r];
          const h2* hh = (const h2*)h2s + cq*4;
          acc2 = dot2w(w4.x, hh[0], acc2);
          acc2 = dot2w(w4.y, hh[1], acc2);
          acc2 = dot2w(w4.z, hh[2], acc2);
          acc2 = dot2w(w4.w, hh[3], acc2);
        }
        acc2 += __shfl_xor(acc2, 1, 64);
        if (!hf) G[(i-1)*144 + r] = acc2;
      }
      if (rr_ == i-1) {                // 4 threads: logit for row i-1
        const h2* hh = (const h2*)h2s + rj*32;
        const h2* vv = (const h2*)v2s + rj*32;
        float acc = 0.f;
        #pragma unroll 8
        for (int q = 0; q < 32; ++q) acc = dot2h(hh[q], vv[q], acc);
        acc += __shfl_xor(acc, 1, 64);
        acc += __shfl_xor(acc, 2, 64);
        if (rj == 0) psum[i-1] = acc;
      }
      if (tid >= 320 && tid < 448) {   // exp + Z over k <= i-2
        int k = tid - 320;
        float e = (k + 1 < i && adj_s[cur][k] != 0) ? __expf(psum[k]) : 0.f;
        aw[k] = e;
        float sv = e;
        #pragma unroll
        for (int off = 32; off >= 1; off >>= 1) sv += __shfl_xor(sv, off, 64);
        if ((k & 63) == 0) red[k >> 6] = sv;
      }
      __syncthreads();                                       // B2

      // ---- post-B2: Gsum + sinv (tid<288) | prefetch i+1 (tid>=288) -------
      if (tid < 288) {
        int r = tid >> 1, kh = tid & 1;
        float e1 = (adj_s[cur][i-1] != 0) ? __expf(psum[i-1]) : 0.f;
        float g = kh ? e1 * G[(i-1)*144 + r] : 0.f;
        int m = i - 1;
        int k0 = kh ? (m >> 1) : 0, k1 = kh ? m : (m >> 1);
        for (int k = k0; k < k1; ++k) g += aw[k] * G[k*144 + r];
        g += __shfl_xor(g, 1, 64);
        if (!kh) Gg[r] = g;
        if (tid == 0) sinv = 1.f / (red[0] + red[1] + e1);
      } else {
        PREF((i < 127) ? i+1 : 127, (i+1) & 1);
      }
      __syncthreads();                                       // B3
    } else {
      if (tid >= 288) PREF(1, 1);
      __syncthreads();
    }

    // ---- gates: 32 lanes, 2 per d (cell 0 = C, cell 1 = P) ----------------
    if (tid < 32) {
      int dl = tid >> 1, cell = tid & 1;
      float inv = (i > 0) ? sinv : 0.f;
      float r0 = 0.f, r1 = 0.f, r2 = 0.f, r3 = 0.f, Mv = 0.f;
      if (i > 0) {
        r0 = Gg[(cell*4+0)*16 + dl] * inv;
        r1 = Gg[(cell*4+1)*16 + dl] * inv;
        r2 = Gg[(cell*4+2)*16 + dl] * inv;
        r3 = Gg[(cell*4+3)*16 + dl] * inv;
        Mv = Gg[128 + dl] * inv;
      }
      float Qv = ql[cur][dl];
      const float* gq = cell ? &gqp_l[cur][0] : &gqc_l[cur][0];
      float xi = cell ? Qv : Mv;
      float gi_ = r0 + gq[ 0 + dl];
      float gf_ = r1 + gq[16 + dl];
      float gg_ = r2 + gq[32 + dl];
      float go_ = r3 + gq[48 + dl];
      float c2  = sigf(gf_)*xi + sigf(gi_)*tanhfast(gg_);
      float ov  = sigf(go_)*tanhfast(c2);
      float htv = ov + __shfl_xor(ov, 1, 64);
      if (!cell) {                     // 16 lanes -> one 64B line store
        __hip_atomic_store(&Hout[((size_t)(b*N_ + i))*D_ + sl*16 + dl], htv,
                           __ATOMIC_RELAXED, __HIP_MEMORY_SCOPE_AGENT);
      }
    }
    // no trailing barrier: wave 0 reaches next B1 only after gates complete;
    // the line store IS the publish signal (consumers poll it directly).
  }
#undef PREF
}

// ---------------------------------------------------------------------------
// Host launch
// ---------------------------------------------------------------------------
extern "C" void kernel_launch(void* const* d_in, const int* in_sizes, int n_in,
                              void* d_out, int out_size, void* d_ws, size_t ws_size,
                              hipStream_t stream)
{
  const float* features = (const float*)d_in[0];
  const int*   adj      = (const int*)  d_in[1];
  const float* fc1_W    = (const float*)d_in[5];
  const float* fc1_b    = (const float*)d_in[6];
  const float* W1       = (const float*)d_in[7];
  const float* W2       = (const float*)d_in[8];
  const float* Wr       = (const float*)d_in[9];
  const float* Wc_ih    = (const float*)d_in[10];
  const float* Wc_hh    = (const float*)d_in[11];
  const float* bc_ih    = (const float*)d_in[12];
  const float* bc_hh    = (const float*)d_in[13];
  const float* Wp_ih    = (const float*)d_in[14];
  const float* Wp_hh    = (const float*)d_in[15];
  const float* bp_ih    = (const float*)d_in[16];
  const float* bp_hh    = (const float*)d_in[17];
  const float* m0_W     = (const float*)d_in[18];
  const float* m0_b     = (const float*)d_in[19];
  const float* m1_W     = (const float*)d_in[20];
  const float* m1_b     = (const float*)d_in[21];
  const float* m2_W     = (const float*)d_in[22];
  const float* m2_b     = (const float*)d_in[23];

  float* ws = (float*)d_ws;
  _Float16* WTP = (_Float16*)ws;     // 1179648 halfs = 589824 float slots
  float* AMAT   = ws + 589824;       // 2 x 65536
  float* H0     = ws + 720896;       // 524288
  float* H1     = ws + 1245184;      // 524288
  float* H2     = ws + 1769472;      // 524288
  float* VMAT   = ws + 2293760;      // 524288
  float* GQC    = ws + 2818048;      // 2097152
  float* GQP    = ws + 4915200;      // 2097152
  float* HB1    = ws + 7012352;      // 524288
  float* HB2    = ws + 7536640;      // 524288

  fill_k<<<128, 256, 0, stream>>>((unsigned*)H1, (unsigned*)H2);
  prepamat_k<<<dim3(4,4,2), 256, 0, stream>>>(W2, W1, AMAT);
  prepnn_k<<<dim3(32,4,2), 256, 0, stream>>>(Wc_hh, Wp_ih, Wr, WTP);
  wrpack_k<<<512, 256, 0, stream>>>(Wr, WTP);

  // H0 = relu(features @ fc1_W^T + b)  (MFMA fp16)
  mfgemm_k<true,true><<<dim3(32,4), 256, 0, stream>>>(features, fc1_W, fc1_b, H0, 2048, 256, 1024);

  // layer 0
  prologue_mf_k<<<dim3(32,36), 256, 0, stream>>>(H0, Wc_ih, Wp_hh, AMAT,
                                                 bc_ih, bc_hh, bp_ih, bp_hh,
                                                 GQC, GQP, VMAT);
  scan_k<<<256, 512, 0, stream>>>(H0, VMAT, GQC, GQP, WTP, adj, H1);

  // layer 1
  prologue_mf_k<<<dim3(32,36), 256, 0, stream>>>(H1, Wc_ih + 262144, Wp_hh + 262144,
                                                 AMAT + 65536,
                                                 bc_ih + 1024, bc_hh + 1024,
                                                 bp_ih + 1024, bp_hh + 1024,
                                                 GQC, GQP, VMAT);
  scan_k<<<256, 512, 0, stream>>>(H1, VMAT, GQC, GQP, WTP + 589824, adj, H2);

  // MLP head
  m0fused_mf_k<<<dim3(32,4), 256, 0, stream>>>(H0, H1, H2, features, m0_W, m0_b, HB1);
  mfgemm_k<true,true><<<dim3(32,4), 256, 0, stream>>>(HB1, m1_W, m1_b, HB2, 2048, 256, 256);
  gemm_k<true,false><<<dim3(32,1), 256, 0, stream>>>(HB2, m2_W, m2_b, (float*)d_out, 2048, 7, 256);
}